// Round 1
// baseline (2144.012 us; speedup 1.0000x reference)
//
#include <hip/hip_runtime.h>

// GraphSAGE, 4 layers, fused aggregation + GEMM per layer. fp32 baseline.
//
// Layer: out[n][c] = relu( sum_k combined[n][k] * W[c][k] )
//   combined[n] = [ h[n] (D_IN)  ||  mean_{j<16} h[neigh[n][j]] (D_IN) ]
//
// Block = 256 threads, BN = 32 nodes per block.
// Phase 1: stage combined[BN][2*D_IN] in LDS (self rows + neighbor mean).
// Phase 2: register-tiled GEMM. thread -> (node = tid%BN, colgroup = tid/BN),
//          CPT = D_OUT*BN/256 cols per thread, float4 k-loop.
//          W reads are same-address across each 32-lane (n) group -> broadcast.

constexpr int N_NODES = 100000;
constexpr int D_FEAT  = 256;
constexpr int HID     = 128;
constexpr int EMB     = 64;
constexpr int FANOUT  = 16;

template<int D_IN, int D_OUT, int BN>
__global__ __launch_bounds__(256)
void sage_layer(const float* __restrict__ h, const int* __restrict__ neigh,
                const float* __restrict__ W, float* __restrict__ out, int N)
{
    constexpr int K   = 2 * D_IN;
    constexpr int LDK = K + 4;             // pad: keeps 16B align, breaks 32-bank stride
    __shared__ float comb[BN * LDK];

    const int node0 = blockIdx.x * BN;
    const int tid   = threadIdx.x;

    // ---- Phase 1a: self rows -> comb[n][0:D_IN] (vectorized float4) ----
    constexpr int SELF_V4 = BN * (D_IN / 4);
    for (int idx = tid; idx < SELF_V4; idx += 256) {
        int n   = idx / (D_IN / 4);
        int f4  = idx % (D_IN / 4);
        int node = node0 + n;
        float4 v = make_float4(0.f, 0.f, 0.f, 0.f);
        if (node < N)
            v = ((const float4*)(h + (size_t)node * D_IN))[f4];
        *((float4*)&comb[n * LDK + f4 * 4]) = v;
    }

    // ---- Phase 1b: neighbor mean -> comb[n][D_IN:2*D_IN] ----
    {
        constexpr int TPN = 256 / BN;       // threads per node
        constexpr int V4  = D_IN / 4;
        int n    = tid / TPN;
        int lane = tid % TPN;
        int node = node0 + n;
        if (node < N) {
            const int* nb = neigh + (size_t)node * FANOUT;
            int ids[FANOUT];
            #pragma unroll
            for (int j = 0; j < FANOUT; ++j) ids[j] = nb[j];
            const float inv = 1.0f / (float)FANOUT;
            for (int f4 = lane; f4 < V4; f4 += TPN) {
                float4 acc = make_float4(0.f, 0.f, 0.f, 0.f);
                #pragma unroll
                for (int j = 0; j < FANOUT; ++j) {
                    float4 v = ((const float4*)(h + (size_t)ids[j] * D_IN))[f4];
                    acc.x += v.x; acc.y += v.y; acc.z += v.z; acc.w += v.w;
                }
                acc.x *= inv; acc.y *= inv; acc.z *= inv; acc.w *= inv;
                *((float4*)&comb[n * LDK + D_IN + f4 * 4]) = acc;
            }
        }
    }
    __syncthreads();

    // ---- Phase 2: mini-GEMM + relu ----
    constexpr int CPT = (D_OUT * BN) / 256;   // cols per thread
    const int n    = tid % BN;
    const int cg   = tid / BN;
    const int c0   = cg * CPT;
    const int node = node0 + n;
    if (node < N) {
        float acc[CPT];
        #pragma unroll
        for (int c = 0; c < CPT; ++c) acc[c] = 0.f;
        const float* cb = &comb[n * LDK];
        for (int k = 0; k < K; k += 4) {
            float4 cv = *((const float4*)&cb[k]);
            #pragma unroll
            for (int c = 0; c < CPT; ++c) {
                float4 wv = *((const float4*)&W[(size_t)(c0 + c) * K + k]);
                acc[c] = fmaf(cv.x, wv.x, acc[c]);
                acc[c] = fmaf(cv.y, wv.y, acc[c]);
                acc[c] = fmaf(cv.z, wv.z, acc[c]);
                acc[c] = fmaf(cv.w, wv.w, acc[c]);
            }
        }
        float* op = out + (size_t)node * D_OUT + c0;
        #pragma unroll
        for (int c = 0; c < CPT; ++c) op[c] = fmaxf(acc[c], 0.f);
    }
}

// out[i][:] = h4[nodes[i]][:]   (nodes is arange in practice, but honor it)
__global__ __launch_bounds__(256)
void gather_out(const float* __restrict__ h4, const int* __restrict__ nodes,
                float* __restrict__ out, int N)
{
    constexpr int E4 = EMB / 4;
    int i = blockIdx.x * blockDim.x + threadIdx.x;
    int total = N * E4;
    if (i < total) {
        int n = i / E4;
        int e = i % E4;
        int src = nodes[n];
        ((float4*)out)[(size_t)n * E4 + e] =
            ((const float4*)h4)[(size_t)src * E4 + e];
    }
}

extern "C" void kernel_launch(void* const* d_in, const int* in_sizes, int n_in,
                              void* d_out, int out_size, void* d_ws, size_t ws_size,
                              hipStream_t stream)
{
    const float* features = (const float*)d_in[0];
    const float* W1       = (const float*)d_in[1];
    const float* W2       = (const float*)d_in[2];
    const float* W3       = (const float*)d_in[3];
    const float* W4       = (const float*)d_in[4];
    const int*   nodes    = (const int*)d_in[5];
    const int*   neigh    = (const int*)d_in[6];
    float*       out      = (float*)d_out;

    // ping-pong h buffers in workspace: 2 x N*HID floats = 102.4 MB
    float* hA = (float*)d_ws;
    float* hB = hA + (size_t)N_NODES * HID;

    constexpr int BN = 32;
    int grid = (N_NODES + BN - 1) / BN;

    sage_layer<D_FEAT, HID, BN><<<grid, 256, 0, stream>>>(features, neigh, W1, hA, N_NODES);
    sage_layer<HID,    HID, BN><<<grid, 256, 0, stream>>>(hA,       neigh, W2, hB, N_NODES);
    sage_layer<HID,    HID, BN><<<grid, 256, 0, stream>>>(hB,       neigh, W3, hA, N_NODES);
    sage_layer<HID,    EMB, BN><<<grid, 256, 0, stream>>>(hA,       neigh, W4, hB, N_NODES);

    int tot = N_NODES * (EMB / 4);
    gather_out<<<(tot + 255) / 256, 256, 0, stream>>>(hB, nodes, out, N_NODES);
}

// Round 2
// 767.294 us; speedup vs baseline: 2.7942x; 2.7942x over previous
//
#include <hip/hip_runtime.h>
#include <hip/hip_bf16.h>

// GraphSAGE restructured: per layer,
//   g = h @ [W_self ; W_neigh]^T   (dense GEMM, fused: C = 2*D_OUT cols)
//   h_next[n] = relu( g_self[n] + (1/16) * sum_j g_neigh[neigh[n][j]] )
// Moves the random gather AFTER the GEMM (D_OUT-wide bf16 rows instead of
// D_IN-wide fp32 rows) and makes the GEMM dense/streaming.

constexpr int N_NODES = 100000;
constexpr int D_FEAT  = 256;
constexpr int HID     = 128;
constexpr int EMB     = 64;
constexpr int FANOUT  = 16;

// ---------- W -> Bt[k][c']  (c'<D_OUT: W[c'][k], else W[c'-D_OUT][D_IN+k]) ----
__global__ __launch_bounds__(256)
void prep_B(const float* __restrict__ W, float* __restrict__ Bt,
            int D_IN, int D_OUT)
{
    int C = 2 * D_OUT;
    int i = blockIdx.x * 256 + threadIdx.x;
    if (i < D_IN * C) {
        int k = i / C;
        int c = i % C;
        float v = (c < D_OUT) ? W[(size_t)c * (2 * D_IN) + k]
                              : W[(size_t)(c - D_OUT) * (2 * D_IN) + D_IN + k];
        Bt[i] = v;
    }
}

// ---------- dense GEMM: g[n][c] = sum_k h[n][k] * Bt[k][c] ----------
// block: 64 nodes x C cols, 256 threads, thread = 4 nodes x CPT cols.
// n_g = tid&15 (node group), c_g = tid>>4 (col group). A-tile transposed in LDS.
template<int K, int C>
__global__ __launch_bounds__(256)
void fused_gemm(const float* __restrict__ h, const float* __restrict__ Bt,
                float* __restrict__ g_self, __hip_bfloat16* __restrict__ g_neigh,
                int N)
{
    constexpr int BN  = 64;
    constexpr int KT  = 32;
    constexpr int CPT = C / 16;          // 16 (C=256) or 8 (C=128)
    constexpr int DO  = C / 2;

    __shared__ float As[KT * BN];        // [k][node] transposed
    __shared__ float Bs[KT * C];         // [k][c]

    const int node0 = blockIdx.x * BN;
    const int tid   = threadIdx.x;
    const int n_g   = tid & 15;
    const int c_g   = tid >> 4;

    float acc[4][CPT];
    #pragma unroll
    for (int i = 0; i < 4; ++i)
        #pragma unroll
        for (int c = 0; c < CPT; ++c) acc[i][c] = 0.f;

    for (int k0 = 0; k0 < K; k0 += KT) {
        // A tile: 64 nodes x 32 k. Each thread loads float4, scatters transposed.
        {
            constexpr int V4 = BN * KT / 4;          // 512 float4
            for (int i = tid; i < V4; i += 256) {
                int row = i / (KT / 4);              // node in tile
                int c4  = i % (KT / 4);              // k-quad
                int node = node0 + row;
                float4 v = make_float4(0.f, 0.f, 0.f, 0.f);
                if (node < N)
                    v = *(const float4*)&h[(size_t)node * K + k0 + c4 * 4];
                As[(c4 * 4 + 0) * BN + row] = v.x;
                As[(c4 * 4 + 1) * BN + row] = v.y;
                As[(c4 * 4 + 2) * BN + row] = v.z;
                As[(c4 * 4 + 3) * BN + row] = v.w;
            }
        }
        // B tile: KT x C floats, coalesced float4
        {
            constexpr int V4 = KT * C / 4;
            for (int i = tid; i < V4; i += 256) {
                *(float4*)&Bs[i * 4] = *(const float4*)&Bt[(size_t)k0 * C + i * 4];
            }
        }
        __syncthreads();

        #pragma unroll 4
        for (int k = 0; k < KT; ++k) {
            float4 av = *(const float4*)&As[k * BN + n_g * 4];
            float4 bv[CPT / 4];
            #pragma unroll
            for (int cc = 0; cc < CPT / 4; ++cc)
                bv[cc] = *(const float4*)&Bs[k * C + c_g * CPT + cc * 4];
            float a4[4] = {av.x, av.y, av.z, av.w};
            #pragma unroll
            for (int i = 0; i < 4; ++i) {
                #pragma unroll
                for (int cc = 0; cc < CPT / 4; ++cc) {
                    acc[i][cc * 4 + 0] = fmaf(a4[i], bv[cc].x, acc[i][cc * 4 + 0]);
                    acc[i][cc * 4 + 1] = fmaf(a4[i], bv[cc].y, acc[i][cc * 4 + 1]);
                    acc[i][cc * 4 + 2] = fmaf(a4[i], bv[cc].z, acc[i][cc * 4 + 2]);
                    acc[i][cc * 4 + 3] = fmaf(a4[i], bv[cc].w, acc[i][cc * 4 + 3]);
                }
            }
        }
        __syncthreads();
    }

    // epilogue: c_g*CPT < DO -> g_self (fp32);  >= DO -> g_neigh (bf16)
    const int cbase = c_g * CPT;
    #pragma unroll
    for (int i = 0; i < 4; ++i) {
        int node = node0 + n_g * 4 + i;
        if (node >= N) continue;
        if (cbase < DO) {
            float* p = g_self + (size_t)node * DO + cbase;
            #pragma unroll
            for (int cc = 0; cc < CPT / 4; ++cc) {
                float4 v = make_float4(acc[i][cc*4+0], acc[i][cc*4+1],
                                       acc[i][cc*4+2], acc[i][cc*4+3]);
                *(float4*)&p[cc * 4] = v;
            }
        } else {
            __hip_bfloat16* p = g_neigh + (size_t)node * DO + (cbase - DO);
            alignas(16) __hip_bfloat16 tmp[CPT];
            #pragma unroll
            for (int c = 0; c < CPT; ++c) tmp[c] = __float2bfloat16(acc[i][c]);
            #pragma unroll
            for (int cc = 0; cc < CPT / 8; ++cc)
                *(uint4*)&p[cc * 8] = *(const uint4*)&tmp[cc * 8];
        }
    }
}

// ---------- aggregation: out[n] = relu(g_self[n] + mean_j g_neigh[nb[j]]) ----
template<int D_OUT>
__global__ __launch_bounds__(256)
void aggregate(const float* __restrict__ g_self,
               const __hip_bfloat16* __restrict__ g_neigh,
               const int* __restrict__ neigh, float* __restrict__ out, int N)
{
    constexpr int LPN = D_OUT / 8;           // lanes per node (8 cols each)
    constexpr int NPB = 256 / LPN;           // nodes per block
    const int tid  = threadIdx.x;
    const int n    = blockIdx.x * NPB + tid / LPN;
    const int lane = tid % LPN;
    if (n >= N) return;

    const int* nb = neigh + (size_t)n * FANOUT;
    int ids[FANOUT];
    #pragma unroll
    for (int j = 0; j < FANOUT; ++j) ids[j] = nb[j];

    float acc[8];
    #pragma unroll
    for (int c = 0; c < 8; ++c) acc[c] = 0.f;

    #pragma unroll
    for (int j = 0; j < FANOUT; ++j) {
        uint4 q = *(const uint4*)&g_neigh[(size_t)ids[j] * D_OUT + lane * 8];
        acc[0] += __uint_as_float(q.x << 16);
        acc[1] += __uint_as_float(q.x & 0xffff0000u);
        acc[2] += __uint_as_float(q.y << 16);
        acc[3] += __uint_as_float(q.y & 0xffff0000u);
        acc[4] += __uint_as_float(q.z << 16);
        acc[5] += __uint_as_float(q.z & 0xffff0000u);
        acc[6] += __uint_as_float(q.w << 16);
        acc[7] += __uint_as_float(q.w & 0xffff0000u);
    }
    const float inv = 1.0f / (float)FANOUT;
    const float* s = g_self + (size_t)n * D_OUT + lane * 8;
    float4 s0 = *(const float4*)&s[0];
    float4 s1 = *(const float4*)&s[4];
    float4 o0, o1;
    o0.x = fmaxf(fmaf(acc[0], inv, s0.x), 0.f);
    o0.y = fmaxf(fmaf(acc[1], inv, s0.y), 0.f);
    o0.z = fmaxf(fmaf(acc[2], inv, s0.z), 0.f);
    o0.w = fmaxf(fmaf(acc[3], inv, s0.w), 0.f);
    o1.x = fmaxf(fmaf(acc[4], inv, s1.x), 0.f);
    o1.y = fmaxf(fmaf(acc[5], inv, s1.y), 0.f);
    o1.z = fmaxf(fmaf(acc[6], inv, s1.z), 0.f);
    o1.w = fmaxf(fmaf(acc[7], inv, s1.w), 0.f);
    float* op = out + (size_t)n * D_OUT + lane * 8;
    *(float4*)&op[0] = o0;
    *(float4*)&op[4] = o1;
}

// ---------- final gather: out[i] = h4[nodes[i]] ----------
__global__ __launch_bounds__(256)
void gather_out(const float* __restrict__ h4, const int* __restrict__ nodes,
                float* __restrict__ out, int N)
{
    constexpr int E4 = EMB / 4;
    int i = blockIdx.x * blockDim.x + threadIdx.x;
    if (i < N * E4) {
        int n = i / E4;
        int e = i % E4;
        int src = nodes[n];
        ((float4*)out)[(size_t)n * E4 + e] =
            ((const float4*)h4)[(size_t)src * E4 + e];
    }
}

extern "C" void kernel_launch(void* const* d_in, const int* in_sizes, int n_in,
                              void* d_out, int out_size, void* d_ws, size_t ws_size,
                              hipStream_t stream)
{
    const float* features = (const float*)d_in[0];
    const float* W1       = (const float*)d_in[1];
    const float* W2       = (const float*)d_in[2];
    const float* W3       = (const float*)d_in[3];
    const float* W4       = (const float*)d_in[4];
    const int*   nodes    = (const int*)d_in[5];
    const int*   neigh    = (const int*)d_in[6];
    float*       out      = (float*)d_out;

    // workspace layout (floats)
    float* Bt1 = (float*)d_ws;                       // 256*256
    float* Bt2 = Bt1 + 256 * 256;                    // 128*256
    float* Bt3 = Bt2 + 128 * 256;                    // 128*256
    float* Bt4 = Bt3 + 128 * 256;                    // 128*128
    float* hA  = Bt4 + 128 * 128;                    // N*128 fp32 (h buffers)
    float* gs  = hA + (size_t)N_NODES * 128;         // N*128 fp32 (g_self)
    __hip_bfloat16* gn = (__hip_bfloat16*)(gs + (size_t)N_NODES * 128); // N*128 bf16

    // prep fused transposed weights
    prep_B<<<(256 * 256 + 255) / 256, 256, 0, stream>>>(W1, Bt1, 256, 128);
    prep_B<<<(128 * 256 + 255) / 256, 256, 0, stream>>>(W2, Bt2, 128, 128);
    prep_B<<<(128 * 256 + 255) / 256, 256, 0, stream>>>(W3, Bt3, 128, 128);
    prep_B<<<(128 * 128 + 255) / 256, 256, 0, stream>>>(W4, Bt4, 128, 64);

    const int gemm_grid = (N_NODES + 63) / 64;

    // L1: K=256, C=256
    fused_gemm<256, 256><<<gemm_grid, 256, 0, stream>>>(features, Bt1, gs, gn, N_NODES);
    aggregate<128><<<(N_NODES + 15) / 16, 256, 0, stream>>>(gs, gn, neigh, hA, N_NODES);
    // L2
    fused_gemm<128, 256><<<gemm_grid, 256, 0, stream>>>(hA, Bt2, gs, gn, N_NODES);
    aggregate<128><<<(N_NODES + 15) / 16, 256, 0, stream>>>(gs, gn, neigh, hA, N_NODES);
    // L3
    fused_gemm<128, 256><<<gemm_grid, 256, 0, stream>>>(hA, Bt3, gs, gn, N_NODES);
    aggregate<128><<<(N_NODES + 15) / 16, 256, 0, stream>>>(gs, gn, neigh, hA, N_NODES);
    // L4: K=128, C=128 (D_OUT=64)
    fused_gemm<128, 128><<<gemm_grid, 256, 0, stream>>>(hA, Bt4, gs, gn, N_NODES);
    aggregate<64><<<(N_NODES + 31) / 32, 256, 0, stream>>>(gs, gn, neigh, hA, N_NODES);

    gather_out<<<(N_NODES * (EMB / 4) + 255) / 256, 256, 0, stream>>>(hA, nodes, out, N_NODES);
}

// Round 3
// 592.113 us; speedup vs baseline: 3.6210x; 1.2959x over previous
//
#include <hip/hip_runtime.h>
#include <hip/hip_bf16.h>

// GraphSAGE: per layer g = h @ Bck^T via split-bf16 MFMA (3-product, fp32-grade),
// then aggregate: h_next[n] = relu(g_self[n] + mean_j g_neigh[neigh[n][j]]).
// Bck[c][k] = fused [W_self ; W_neigh] pre-transposed to [c][k], stored as
// bf16 hi+lo planes. A (=h, fp32) split to hi/lo bf16 at LDS staging time.

constexpr int N_NODES = 100000;
constexpr int EMB     = 64;
constexpr int FANOUT  = 16;

typedef __attribute__((ext_vector_type(8))) short short8;
typedef __attribute__((ext_vector_type(4))) float f32x4;

__device__ inline unsigned short bf16_rne(float f) {
    unsigned u = __float_as_uint(f);
    return (unsigned short)((u + 0x7fffu + ((u >> 16) & 1u)) >> 16);
}
__device__ inline float bf16_tof(unsigned short s) {
    return __uint_as_float(((unsigned)s) << 16);
}

// ---- weights -> Bck hi/lo bf16, layout [c][k], c in [0,2*D_OUT), k in [0,D_IN) ----
__global__ __launch_bounds__(256)
void prep_Bck(const float* __restrict__ W, unsigned short* __restrict__ Bhi,
              unsigned short* __restrict__ Blo, int D_IN, int D_OUT)
{
    int i = blockIdx.x * 256 + threadIdx.x;
    int total = 2 * D_OUT * D_IN;
    if (i >= total) return;
    int c = i / D_IN, k = i % D_IN;
    float v = (c < D_OUT) ? W[(size_t)c * (2 * D_IN) + k]
                          : W[(size_t)(c - D_OUT) * (2 * D_IN) + D_IN + k];
    unsigned short hi = bf16_rne(v);
    Bhi[i] = hi;
    Blo[i] = bf16_rne(v - bf16_tof(hi));
}

// ---- MFMA GEMM: g[n][c] = sum_k h[n][k] * Bck[c][k] ----
// block: 64 nodes x C cols, 4 waves split N (each 64x(C/4)).
// LDS rows padded to 40 bf16 (80 B = 5x16B): b128 frag reads are 2-way (free).
template<int K, int C>
__global__ __launch_bounds__(256, 2)
void mfma_gemm(const float* __restrict__ h,
               const unsigned short* __restrict__ Bhi,
               const unsigned short* __restrict__ Blo,
               float* __restrict__ g_self,
               __hip_bfloat16* __restrict__ g_neigh, int N)
{
    constexpr int DO   = C / 2;
    constexpr int NSUB = C / 64;          // 16-col subtiles per wave: 4 (C=256) / 2 (C=128)
    constexpr int LDA  = 40;
    __shared__ unsigned short Ah[64 * LDA], Al[64 * LDA];
    __shared__ unsigned short Bh[C * LDA], Bl[C * LDA];

    const int tid   = threadIdx.x;
    const int wave  = tid >> 6;
    const int lane  = tid & 63;
    const int ml    = lane & 15;
    const int quad  = lane >> 4;
    const int node0 = blockIdx.x * 64;

    f32x4 acc[4][NSUB];
    #pragma unroll
    for (int mi = 0; mi < 4; ++mi)
        #pragma unroll
        for (int ni = 0; ni < NSUB; ++ni)
            acc[mi][ni] = (f32x4){0.f, 0.f, 0.f, 0.f};

    for (int k0 = 0; k0 < K; k0 += 32) {
        // stage A: 64 rows x 32 k, fp32 -> hi/lo bf16
        #pragma unroll
        for (int i = tid; i < 512; i += 256) {
            int row = i >> 3, ch = i & 7;
            int node = node0 + row;
            float4 v = make_float4(0.f, 0.f, 0.f, 0.f);
            if (node < N)
                v = *(const float4*)&h[(size_t)node * K + k0 + ch * 4];
            unsigned short hi[4], lo[4];
            const float* pf = &v.x;
            #pragma unroll
            for (int e = 0; e < 4; ++e) {
                hi[e] = bf16_rne(pf[e]);
                lo[e] = bf16_rne(pf[e] - bf16_tof(hi[e]));
            }
            *(uint2*)&Ah[row * LDA + ch * 4] = *(const uint2*)hi;
            *(uint2*)&Al[row * LDA + ch * 4] = *(const uint2*)lo;
        }
        // stage B: C rows x 32 k (bf16 hi/lo straight copies)
        for (int i = tid; i < C * 4; i += 256) {
            int c = i >> 2, ch = i & 3;
            *(uint4*)&Bh[c * LDA + ch * 8] = *(const uint4*)&Bhi[(size_t)c * K + k0 + ch * 8];
            *(uint4*)&Bl[c * LDA + ch * 8] = *(const uint4*)&Blo[(size_t)c * K + k0 + ch * 8];
        }
        __syncthreads();

        short8 afh[4], afl[4], bfh[NSUB], bfl[NSUB];
        #pragma unroll
        for (int mi = 0; mi < 4; ++mi) {
            afh[mi] = *(const short8*)&Ah[(mi * 16 + ml) * LDA + quad * 8];
            afl[mi] = *(const short8*)&Al[(mi * 16 + ml) * LDA + quad * 8];
        }
        #pragma unroll
        for (int ni = 0; ni < NSUB; ++ni) {
            int c = wave * (16 * NSUB) + ni * 16 + ml;
            bfh[ni] = *(const short8*)&Bh[c * LDA + quad * 8];
            bfl[ni] = *(const short8*)&Bl[c * LDA + quad * 8];
        }
        #pragma unroll
        for (int mi = 0; mi < 4; ++mi)
            #pragma unroll
            for (int ni = 0; ni < NSUB; ++ni) {
                acc[mi][ni] = __builtin_amdgcn_mfma_f32_16x16x32_bf16(afl[mi], bfh[ni], acc[mi][ni], 0, 0, 0);
                acc[mi][ni] = __builtin_amdgcn_mfma_f32_16x16x32_bf16(afh[mi], bfl[ni], acc[mi][ni], 0, 0, 0);
                acc[mi][ni] = __builtin_amdgcn_mfma_f32_16x16x32_bf16(afh[mi], bfh[ni], acc[mi][ni], 0, 0, 0);
            }
        __syncthreads();
    }

    // epilogue: D row = quad*4+r, col = ml (verified m89 layout)
    #pragma unroll
    for (int mi = 0; mi < 4; ++mi) {
        #pragma unroll
        for (int r = 0; r < 4; ++r) {
            int node = node0 + mi * 16 + quad * 4 + r;
            if (node >= N) continue;
            #pragma unroll
            for (int ni = 0; ni < NSUB; ++ni) {
                int c = wave * (16 * NSUB) + ni * 16 + ml;
                float v = acc[mi][ni][r];
                if (c < DO)
                    g_self[(size_t)node * DO + c] = v;
                else
                    *(unsigned short*)&g_neigh[(size_t)node * DO + (c - DO)] = bf16_rne(v);
            }
        }
    }
}

// ---- aggregation: out[n] = relu(g_self[n] + mean_j g_neigh[nb[j]]) ----
template<int D_OUT>
__global__ __launch_bounds__(256)
void aggregate(const float* __restrict__ g_self,
               const __hip_bfloat16* __restrict__ g_neigh,
               const int* __restrict__ neigh, float* __restrict__ out, int N)
{
    constexpr int LPN = D_OUT / 8;
    constexpr int NPB = 256 / LPN;
    const int tid  = threadIdx.x;
    const int n    = blockIdx.x * NPB + tid / LPN;
    const int lane = tid % LPN;
    if (n >= N) return;

    const int* nb = neigh + (size_t)n * FANOUT;
    int ids[FANOUT];
    #pragma unroll
    for (int j = 0; j < FANOUT; ++j) ids[j] = nb[j];

    float acc[8];
    #pragma unroll
    for (int c = 0; c < 8; ++c) acc[c] = 0.f;

    #pragma unroll
    for (int j = 0; j < FANOUT; ++j) {
        uint4 q = *(const uint4*)&g_neigh[(size_t)ids[j] * D_OUT + lane * 8];
        acc[0] += __uint_as_float(q.x << 16);
        acc[1] += __uint_as_float(q.x & 0xffff0000u);
        acc[2] += __uint_as_float(q.y << 16);
        acc[3] += __uint_as_float(q.y & 0xffff0000u);
        acc[4] += __uint_as_float(q.z << 16);
        acc[5] += __uint_as_float(q.z & 0xffff0000u);
        acc[6] += __uint_as_float(q.w << 16);
        acc[7] += __uint_as_float(q.w & 0xffff0000u);
    }
    const float inv = 1.0f / (float)FANOUT;
    const float* s = g_self + (size_t)n * D_OUT + lane * 8;
    float4 s0 = *(const float4*)&s[0];
    float4 s1 = *(const float4*)&s[4];
    float4 o0, o1;
    o0.x = fmaxf(fmaf(acc[0], inv, s0.x), 0.f);
    o0.y = fmaxf(fmaf(acc[1], inv, s0.y), 0.f);
    o0.z = fmaxf(fmaf(acc[2], inv, s0.z), 0.f);
    o0.w = fmaxf(fmaf(acc[3], inv, s0.w), 0.f);
    o1.x = fmaxf(fmaf(acc[4], inv, s1.x), 0.f);
    o1.y = fmaxf(fmaf(acc[5], inv, s1.y), 0.f);
    o1.z = fmaxf(fmaf(acc[6], inv, s1.z), 0.f);
    o1.w = fmaxf(fmaf(acc[7], inv, s1.w), 0.f);
    float* op = out + (size_t)n * D_OUT + lane * 8;
    *(float4*)&op[0] = o0;
    *(float4*)&op[4] = o1;
}

// ---- final gather: out[i] = h4[nodes[i]] ----
__global__ __launch_bounds__(256)
void gather_out(const float* __restrict__ h4, const int* __restrict__ nodes,
                float* __restrict__ out, int N)
{
    constexpr int E4 = EMB / 4;
    int i = blockIdx.x * blockDim.x + threadIdx.x;
    if (i < N * E4) {
        int n = i / E4;
        int e = i % E4;
        int src = nodes[n];
        ((float4*)out)[(size_t)n * E4 + e] =
            ((const float4*)h4)[(size_t)src * E4 + e];
    }
}

extern "C" void kernel_launch(void* const* d_in, const int* in_sizes, int n_in,
                              void* d_out, int out_size, void* d_ws, size_t ws_size,
                              hipStream_t stream)
{
    const float* features = (const float*)d_in[0];
    const float* W1       = (const float*)d_in[1];
    const float* W2       = (const float*)d_in[2];
    const float* W3       = (const float*)d_in[3];
    const float* W4       = (const float*)d_in[4];
    const int*   nodes    = (const int*)d_in[5];
    const int*   neigh    = (const int*)d_in[6];
    float*       out      = (float*)d_out;

    // workspace layout
    unsigned short* B1h = (unsigned short*)d_ws;        // 256x256
    unsigned short* B1l = B1h + 65536;
    unsigned short* B2h = B1l + 65536;                  // 256x128
    unsigned short* B2l = B2h + 32768;
    unsigned short* B3h = B2l + 32768;
    unsigned short* B3l = B3h + 32768;
    unsigned short* B4h = B3l + 32768;                  // 128x128
    unsigned short* B4l = B4h + 16384;
    float* hA = (float*)(B4l + 16384);                  // N*128 fp32
    float* gs = hA + (size_t)N_NODES * 128;             // N*128 fp32
    __hip_bfloat16* gn = (__hip_bfloat16*)(gs + (size_t)N_NODES * 128); // N*128 bf16

    prep_Bck<<<(65536 + 255) / 256, 256, 0, stream>>>(W1, B1h, B1l, 256, 128);
    prep_Bck<<<(32768 + 255) / 256, 256, 0, stream>>>(W2, B2h, B2l, 128, 128);
    prep_Bck<<<(32768 + 255) / 256, 256, 0, stream>>>(W3, B3h, B3l, 128, 128);
    prep_Bck<<<(16384 + 255) / 256, 256, 0, stream>>>(W4, B4h, B4l, 128, 64);

    const int gemm_grid = (N_NODES + 63) / 64;

    mfma_gemm<256, 256><<<gemm_grid, 256, 0, stream>>>(features, B1h, B1l, gs, gn, N_NODES);
    aggregate<128><<<(N_NODES + 15) / 16, 256, 0, stream>>>(gs, gn, neigh, hA, N_NODES);

    mfma_gemm<128, 256><<<gemm_grid, 256, 0, stream>>>(hA, B2h, B2l, gs, gn, N_NODES);
    aggregate<128><<<(N_NODES + 15) / 16, 256, 0, stream>>>(gs, gn, neigh, hA, N_NODES);

    mfma_gemm<128, 256><<<gemm_grid, 256, 0, stream>>>(hA, B3h, B3l, gs, gn, N_NODES);
    aggregate<128><<<(N_NODES + 15) / 16, 256, 0, stream>>>(gs, gn, neigh, hA, N_NODES);

    mfma_gemm<128, 128><<<gemm_grid, 256, 0, stream>>>(hA, B4h, B4l, gs, gn, N_NODES);
    aggregate<64><<<(N_NODES + 31) / 32, 256, 0, stream>>>(gs, gn, neigh, hA, N_NODES);

    gather_out<<<(N_NODES * (EMB / 4) + 255) / 256, 256, 0, stream>>>(hA, nodes, out, N_NODES);
}